// Round 3
// baseline (462.855 us; speedup 1.0000x reference)
//
#include <hip/hip_runtime.h>
#include <hip/hip_bf16.h>
#include <math.h>

// Problem shape (fixed by setup_inputs): B=128, S=20, C=32000
#define NB 128
#define NS 20
#define NC 32000
#define BPB 32            // batches per Hungarian block (one thread per batch)
#define NHB (NB / BPB)    // 4 Hungarian blocks
#define CST 401           // per-thread cost stride in floats (odd -> no LDS bank conflict)

// ---------------------------------------------------------------------------
// Mega kernel, heterogeneous blocks:
//   blockIdx.x <  NHB : fused gather + restricted-softmax cost + SCALAR
//                       Hungarian (thread t owns batch b0+t entirely; all
//                       j-loops unrolled, v/minv in registers, u/p/way in LDS)
//   blockIdx.x >= NHB : per-row logsumexp over C=32000 (HBM-bound stream)
// The 4 Hungarian blocks are throughput-bound (no cross-lane ops) and hide
// completely under the 2560-block HBM stream.
// ---------------------------------------------------------------------------
__global__ __launch_bounds__(256) void mega_kernel(
        const float* __restrict__ outputs,
        const int* __restrict__ gold,
        const float* __restrict__ weight,
        int* __restrict__ match_col,     // [NB*NS] assigned 0-based column per row
        float* __restrict__ sub_ws,      // [NB*NS*NS] raw gathered logits (for final)
        float* __restrict__ logZ) {      // [NB*NS]

    if (blockIdx.x < NHB) {
        // =================== fused cost + scalar Hungarian ===================
        __shared__ float  cst[BPB * CST];      // 51,328 B: per-thread 20x20 cost
        __shared__ double u_sh[BPB][21];       //  5,376 B: row potentials
        __shared__ float  lzrow[BPB * NS];     //  2,560 B
        __shared__ int    way_sh[BPB][21];     //  2,688 B
        __shared__ int    p_sh[BPB][21];       //  2,688 B   (total ~63.1 KB)

        const int b0 = blockIdx.x * BPB;

        // phase 1: gather outputs[b, i, gold[b, j]] into LDS + save to ws
        for (int e = threadIdx.x; e < BPB * NS * NS; e += 256) {
            int bb = e / (NS * NS); int rem = e - bb * (NS * NS);
            int i = rem / NS; int j = rem - i * NS;
            int b = b0 + bb;
            int gc = gold[b * NS + j];
            float x = outputs[(size_t)(b * NS + i) * NC + gc];
            cst[bb * CST + i * NS + j] = x;
            sub_ws[(size_t)(b * NS + i) * NS + j] = x;
        }
        __syncthreads();
        // phase 2: per-row restricted logsumexp (BPB*NS = 640 rows)
        for (int r = threadIdx.x; r < BPB * NS; r += 256) {
            int bb = r / NS; int i = r - bb * NS;
            const float* row = &cst[bb * CST + i * NS];
            float mx = row[0];
#pragma unroll
            for (int j = 1; j < NS; ++j) mx = fmaxf(mx, row[j]);
            float s = 0.f;
#pragma unroll
            for (int j = 0; j < NS; ++j) s += __expf(row[j] - mx);
            lzrow[r] = mx + __logf(s);
        }
        __syncthreads();
        // phase 3: cost = -(x - lz) * w[gold[j]]  (BIG replaces inf), in place
        for (int e = threadIdx.x; e < BPB * NS * NS; e += 256) {
            int bb = e / (NS * NS); int rem = e - bb * (NS * NS);
            int i = rem / NS; int j = rem - i * NS;
            int b = b0 + bb;
            float w = weight[gold[b * NS + j]];
            float c = -(cst[bb * CST + i * NS + j] - lzrow[bb * NS + i]) * w;
            if (isinf(c)) c = 1e8f;
            cst[bb * CST + i * NS + j] = c;
        }
        // init u / p / way
        for (int e = threadIdx.x; e < BPB * 21; e += 256) {
            ((double*)u_sh)[e] = 0.0;
            ((int*)p_sh)[e] = 0;
            ((int*)way_sh)[e] = 0;
        }
        __syncthreads();
        if (threadIdx.x >= BPB) return;   // only 32 solver lanes

        // ---- scalar shortest-augmenting-path Hungarian, one batch per lane ----
        const int t = threadIdx.x;
        const float* C = &cst[t * CST];    // [20][20], row-major i*NS+j
        double* u   = u_sh[t];             // [21], u[0] unused
        int*    way = way_sh[t];
        int*    p   = p_sh[t];             // p[j]: row matched to col j (0 free)
        const double DINF = (double)INFINITY;
        double v[NS + 1], minv[NS + 1];
#pragma unroll
        for (int j = 1; j <= NS; ++j) v[j] = 0.0;

        for (int i = 1; i <= NS; ++i) {
            int j0 = 0;
#pragma unroll
            for (int j = 1; j <= NS; ++j) minv[j] = DINF;
            unsigned usedMask = 0u;   // bit j: column j used (incl. j=0)
            unsigned actMask  = 0u;   // bit r: row r in p[used]
            while (true) {
                usedMask |= 1u << j0;
                int i0 = (j0 == 0) ? i : p[j0];
                actMask |= 1u << i0;
                double u_i0 = u[i0];
                const float* crow = &C[(i0 - 1) * NS];
                double best = DINF; int j1 = 0;
#pragma unroll
                for (int j = 1; j <= NS; ++j) {
                    if (!((usedMask >> j) & 1u)) {
                        double cur = (double)crow[j - 1] - u_i0 - v[j];
                        if (cur < minv[j]) { minv[j] = cur; way[j] = j0; }
                        if (minv[j] < best) { best = minv[j]; j1 = j; } // strict < => np.argmin tie-break
                    }
                }
                double delta = best;
                // u[p[used]] += delta  (exact per-iteration update, as reference)
                unsigned am = actMask;
                while (am) { int r = __ffs(am) - 1; am &= am - 1; u[r] += delta; }
#pragma unroll
                for (int j = 1; j <= NS; ++j) {
                    if ((usedMask >> j) & 1u) v[j] -= delta;
                    else                      minv[j] -= delta;
                }
                j0 = j1;
                if (p[j0] == 0) break;    // reached a free column
            }
            // augment along way[] chain
            while (j0 != 0) {
                int j1 = way[j0];
                p[j0] = (j1 == 0) ? i : p[j1];
                j0 = j1;
            }
        }
        // ans[p[j]-1] = j-1
#pragma unroll
        for (int j = 1; j <= NS; ++j) {
            match_col[(b0 + t) * NS + (p[j] - 1)] = j - 1;
        }
    } else {
        // =================== per-row logZ over C ===================
        const int row = blockIdx.x - NHB;
        const float4* rp = (const float4*)(outputs + (size_t)row * NC);
        const int n4 = NC / 4;   // 8000

        float m = -INFINITY;
        float s = 0.f;
        for (int idx = threadIdx.x; idx < n4; idx += blockDim.x) {
            float4 x = rp[idx];
            float m4 = fmaxf(fmaxf(x.x, x.y), fmaxf(x.z, x.w));
            float nm = fmaxf(m, m4);
            s = s * __expf(m - nm)
              + __expf(x.x - nm) + __expf(x.y - nm)
              + __expf(x.z - nm) + __expf(x.w - nm);
            m = nm;
        }
        for (int off = 1; off < 64; off <<= 1) {
            float om = __shfl_xor(m, off);
            float os = __shfl_xor(s, off);
            float nm = fmaxf(m, om);
            s = s * __expf(m - nm) + os * __expf(om - nm);
            m = nm;
        }
        __shared__ float smx[4], ssm[4];
        int wid = threadIdx.x >> 6;
        if ((threadIdx.x & 63) == 0) { smx[wid] = m; ssm[wid] = s; }
        __syncthreads();
        if (threadIdx.x == 0) {
            float M = smx[0], S = ssm[0];
            for (int w = 1; w < 4; ++w) {
                float om = smx[w], os = ssm[w];
                float nm = fmaxf(M, om);
                S = S * __expf(M - nm) + os * __expf(om - nm);
                M = nm;
            }
            logZ[row] = M + __logf(S);
        }
    }
}

// ---------------------------------------------------------------------------
// Final masked-mean NLL reduce — everything L2-hot (sub_ws, logZ, match_col).
// Deterministic tree reduce, f64 accumulation.
// ---------------------------------------------------------------------------
__global__ __launch_bounds__(256) void final_kernel(
        const int* __restrict__ match_col,
        const float* __restrict__ sub_ws,
        const float* __restrict__ logZ,
        const float* __restrict__ weight,
        const int* __restrict__ gold,
        const unsigned char* __restrict__ mask,
        float* __restrict__ out) {
    double nsum = 0.0, msum = 0.0;
    for (int r = threadIdx.x; r < NB * NS; r += 256) {
        int b = r / NS;
        int col = match_col[r];
        float x = sub_ws[(size_t)r * NS + col];          // outputs[b,i,match]
        float w = weight[gold[b * NS + col]];            // weight[match]
        float nll = -(x - logZ[r]) * w;
        float mk = mask[r] ? 1.f : 0.f;
        nsum += (double)(nll * mk);
        msum += (double)mk;
    }
    for (int off = 1; off < 64; off <<= 1) {
        nsum += __shfl_xor(nsum, off);
        msum += __shfl_xor(msum, off);
    }
    __shared__ double sn[4], sm[4];
    int wid = threadIdx.x >> 6;
    if ((threadIdx.x & 63) == 0) { sn[wid] = nsum; sm[wid] = msum; }
    __syncthreads();
    if (threadIdx.x == 0) {
        double N = 0.0, M = 0.0;
        for (int w = 0; w < 4; ++w) { N += sn[w]; M += sm[w]; }
        out[0] = (float)(N / (M + 1e-8));
    }
}

// ---------------------------------------------------------------------------
extern "C" void kernel_launch(void* const* d_in, const int* in_sizes, int n_in,
                              void* d_out, int out_size, void* d_ws, size_t ws_size,
                              hipStream_t stream) {
    const float* outputs        = (const float*)d_in[0];          // [B,S,C] f32
    const int*   gold           = (const int*)d_in[1];            // [B,S] i32
    const unsigned char* mask   = (const unsigned char*)d_in[2];  // [B,S] bool
    const float* weight         = (const float*)d_in[3];          // [C] f32
    float* out = (float*)d_out;

    // workspace layout
    char* ws = (char*)d_ws;
    int*   match_col = (int*)ws;                                   // NB*NS
    float* logZ      = (float*)(ws + (size_t)NB * NS * 4);         // NB*NS
    float* sub_ws    = (float*)(ws + (size_t)NB * NS * 8);         // NB*NS*NS

    mega_kernel<<<NHB + NB * NS, 256, 0, stream>>>(outputs, gold, weight,
                                                   match_col, sub_ws, logZ);
    final_kernel<<<1, 256, 0, stream>>>(match_col, sub_ws, logZ, weight, gold,
                                        mask, out);
}